// Round 2
// baseline (2461.316 us; speedup 1.0000x reference)
//
#include <hip/hip_runtime.h>
#include <stdint.h>

// Problem constants
#define BB   64
#define TT   512
#define HT   256
#define OO   128
#define GATES 1024   // 4*H

// ---------------------------------------------------------------------------
// R11 recurrence: MFMA-based. gates[1024] = Whh[1024x256] @ h[256] per block
// (one batch element). 8 waves: s=w&1 owns k-half [128s,128s+128),
// r=w>>1 owns row quarter [256r,256r+256).  Per wave: 16 row-tiles (rt) x
// 4 k-tiles (kt) of mfma_f32_16x16x32_f16; B operand = h chunk broadcast
// into all 16 columns (cols redundant; only col-0 lanes store D).
// Weights are MFMA A-operands -> live in AGPRs with ZERO move cost (R10's
// fdot2 needed v_accvgpr_read per use: ~1300cy/step of VALU plumbing).
// Frag split per wave (64 total): 40 reg / 18 LDS (144KB) / 6 L2-stream.
#define RFRAG 40
#define LFRAG 18
#define SFRAG 6

typedef _Float16 half_t;
typedef _Float16 half2_t __attribute__((ext_vector_type(2)));
typedef _Float16 f16x8  __attribute__((ext_vector_type(8)));
typedef float    f32x4  __attribute__((ext_vector_type(4)));

// lgkm-only workgroup barrier (R9 win): no vmcnt drain per step.
#define WG_BARRIER() do { __builtin_amdgcn_s_waitcnt(0xC07F); \
                          __builtin_amdgcn_s_barrier(); } while (0)

__device__ __forceinline__ float fast_sig(float x) {
    return __builtin_amdgcn_rcpf(1.0f + __expf(-x));
}
__device__ __forceinline__ float fast_tanh(float x) {
    float t = __expf(2.0f * x);
    return 1.0f - 2.0f * __builtin_amdgcn_rcpf(t + 1.0f);
}

// ---------------------------------------------------------------------------
// Embedding gather + decoder_action output
__global__ __launch_bounds__(256) void embed_kernel(
    const int* __restrict__ actions, const float* __restrict__ emb_table,
    float* __restrict__ X, float* __restrict__ dact)
{
    int row = blockIdx.x;
    int t = row & (TT - 1);
    int id = (t == 0) ? 0 : actions[row - 1];
    X[(int64_t)row * HT + threadIdx.x] = emb_table[(int64_t)id * HT + threadIdx.x];
    if (threadIdx.x == 0) dact[row] = (float)actions[row];
}

// ---------------------------------------------------------------------------
// Repack Whh to fp16 MFMA A-fragment layout.
// Output index (per layer, 32768 uint4): (w*64 + pos)*64 + lane, where
// frag f = rt*4+kt maps to storage pos: kt<2 -> rt*2+kt (REG 0..31);
// kt==2: rt<8 -> 32+rt (REG), else 40+(rt-8) (LDS 0..7);
// kt==3: rt<10 -> 48+rt (LDS 8..17), else 58+(rt-10) (STREAM 0..5).
// Lane holds A[row= 256r+16rt+(lane&15)][k= 128s+32kt+(lane>>4)*8 .. +7].
__global__ __launch_bounds__(256) void repack_whh_mfma_kernel(
    const float* __restrict__ Whh, uint4* __restrict__ Wpkh)
{
    int idx  = blockIdx.x * 256 + threadIdx.x;  // 0..65535
    int lane = idx & 63;
    int f    = (idx >> 6) & 63;
    int w    = (idx >> 12) & 7;
    int l    = idx >> 15;
    int s = w & 1, r = w >> 1;
    int rt = f >> 2, kt = f & 3;

    int pos;
    if (kt < 2)       pos = rt * 2 + kt;
    else if (kt == 2) pos = (rt < 8)  ? (32 + rt) : (40 + (rt - 8));
    else              pos = (rt < 10) ? (48 + rt) : (58 + (rt - 10));

    int row  = 256 * r + 16 * rt + (lane & 15);
    int kcol = 128 * s + 32 * kt + (lane >> 4) * 8;
    const float* src = Whh + (int64_t)l * (GATES * HT) + (int64_t)row * HT + kcol;
    const float4 a = *(const float4*)(src);
    const float4 b = *(const float4*)(src + 4);
    half2_t p0 = {(half_t)a.x, (half_t)a.y};
    half2_t p1 = {(half_t)a.z, (half_t)a.w};
    half2_t p2 = {(half_t)b.x, (half_t)b.y};
    half2_t p3 = {(half_t)b.z, (half_t)b.w};
    uint4 o;
    o.x = __builtin_bit_cast(unsigned int, p0);
    o.y = __builtin_bit_cast(unsigned int, p1);
    o.z = __builtin_bit_cast(unsigned int, p2);
    o.w = __builtin_bit_cast(unsigned int, p3);
    Wpkh[(int64_t)l * 32768 + ((w * 64 + pos) * 64 + lane)] = o;
}

// ---------------------------------------------------------------------------
// MFMA fp16 GEMM: C = act( A @ op(B) + bias1 + bias2 ), fp32 in/out.
template<bool TRANS_B, int ACT>
__global__ __launch_bounds__(256) void mfma_gemm_kernel(
    const float* __restrict__ A, const float* __restrict__ Bm,
    float* __restrict__ C,
    int K, int lda, int ldb, int ldc,
    int64_t sA, int64_t sB, int64_t sC,
    const float* __restrict__ bias1, const float* __restrict__ bias2)
{
    constexpr int BM = 128, BN = 128, BK = 32;
    constexpr int LDT = BK + 8;                  // 40 halfs = 80 B row stride
    __shared__ __align__(16) half_t Asl[BM * LDT];   // 10 KB
    __shared__ __align__(16) half_t Bsl[BN * LDT];   // 10 KB

    const int tid  = threadIdx.x;
    const int wave = tid >> 6;
    const int lane = tid & 63;
    const int wm = (wave & 1) * 64;
    const int wn = (wave >> 1) * 64;
    const int m0 = blockIdx.y * BM;
    const int n0 = blockIdx.x * BN;
    A  += (int64_t)blockIdx.z * sA;
    Bm += (int64_t)blockIdx.z * sB;
    C  += (int64_t)blockIdx.z * sC;

    const int fm = lane & 15;
    const int qd = lane >> 4;

    f32x4 acc[4][4] = {};

    for (int k0 = 0; k0 < K; k0 += BK) {
        #pragma unroll
        for (int i = 0; i < 4; i++) {
            int idx = tid + i * 256;             // 0..1023
            int r  = idx >> 3;                   // 0..127
            int kq = idx & 7;                    // 0..7
            float4 v = *(const float4*)(A + (int64_t)(m0 + r) * lda + k0 + kq * 4);
            half_t* d = &Asl[r * LDT + kq * 4];
            d[0] = (half_t)v.x; d[1] = (half_t)v.y;
            d[2] = (half_t)v.z; d[3] = (half_t)v.w;
        }
        if (TRANS_B) {
            #pragma unroll
            for (int i = 0; i < 4; i++) {
                int idx = tid + i * 256;
                int r  = idx >> 3;
                int kq = idx & 7;
                float4 v = *(const float4*)(Bm + (int64_t)(n0 + r) * ldb + k0 + kq * 4);
                half_t* d = &Bsl[r * LDT + kq * 4];
                d[0] = (half_t)v.x; d[1] = (half_t)v.y;
                d[2] = (half_t)v.z; d[3] = (half_t)v.w;
            }
        } else {
            #pragma unroll
            for (int i = 0; i < 4; i++) {
                int idx = tid + i * 256;
                int kk = idx >> 5;               // 0..31
                int nq = idx & 31;               // 0..31 (x4 n)
                float4 v = *(const float4*)(Bm + (int64_t)(k0 + kk) * ldb + n0 + nq * 4);
                Bsl[(nq * 4 + 0) * LDT + kk] = (half_t)v.x;
                Bsl[(nq * 4 + 1) * LDT + kk] = (half_t)v.y;
                Bsl[(nq * 4 + 2) * LDT + kk] = (half_t)v.z;
                Bsl[(nq * 4 + 3) * LDT + kk] = (half_t)v.w;
            }
        }
        __syncthreads();

        f16x8 af[4], bf[4];
        #pragma unroll
        for (int t = 0; t < 4; t++)
            af[t] = *(const f16x8*)&Asl[(wm + t * 16 + fm) * LDT + qd * 8];
        #pragma unroll
        for (int t = 0; t < 4; t++)
            bf[t] = *(const f16x8*)&Bsl[(wn + t * 16 + fm) * LDT + qd * 8];
        #pragma unroll
        for (int mt = 0; mt < 4; mt++)
            #pragma unroll
            for (int nt = 0; nt < 4; nt++)
                acc[mt][nt] = __builtin_amdgcn_mfma_f32_16x16x32_f16(
                                  af[mt], bf[nt], acc[mt][nt], 0, 0, 0);
        __syncthreads();
    }

    #pragma unroll
    for (int nt = 0; nt < 4; nt++) {
        int n = n0 + wn + nt * 16 + fm;
        float bv = 0.0f;
        if (bias1) bv += bias1[n];
        if (bias2) bv += bias2[n];
        #pragma unroll
        for (int mt = 0; mt < 4; mt++) {
            #pragma unroll
            for (int r = 0; r < 4; r++) {
                int m = m0 + wm + mt * 16 + qd * 4 + r;
                float v = acc[mt][nt][r] + bv;
                if (ACT == 1) v = tanhf(v);
                C[(int64_t)m * ldc + n] = v;
            }
        }
    }
}

// ---------------------------------------------------------------------------
// Generic fp32 tiled GEMM (kept for attention + output chain precision).
template<bool TRANS_B, int ACT>
__global__ __launch_bounds__(256) void gemm128_kernel(
    const float* __restrict__ A, const float* __restrict__ Bm,
    float* __restrict__ C,
    int K, int lda, int ldb, int ldc,
    int64_t sA, int64_t sB, int64_t sC,
    const float* __restrict__ bias1, const float* __restrict__ bias2)
{
    constexpr int BM = 128, BN = 128, BK = 16;
    __shared__ __align__(16) float As[BK][BM + 4];
    __shared__ __align__(16) float Bs[BK][BN + 4];

    const int tid = threadIdx.x;
    const int m0 = blockIdx.y * BM;
    const int n0 = blockIdx.x * BN;
    A  += (int64_t)blockIdx.z * sA;
    Bm += (int64_t)blockIdx.z * sB;
    C  += (int64_t)blockIdx.z * sC;

    const int tm = tid & 15;
    const int tn = tid >> 4;

    float acc[8][8] = {};

    for (int k0 = 0; k0 < K; k0 += BK) {
        #pragma unroll
        for (int i = 0; i < 2; i++) {
            int idx = tid + i * 256;
            int ar = idx >> 2;
            int ak = (idx & 3) * 4;
            const float4 v = *(const float4*)(A + (int64_t)(m0 + ar) * lda + k0 + ak);
            As[ak + 0][ar] = v.x; As[ak + 1][ar] = v.y;
            As[ak + 2][ar] = v.z; As[ak + 3][ar] = v.w;
        }
        if (TRANS_B) {
            #pragma unroll
            for (int i = 0; i < 2; i++) {
                int idx = tid + i * 256;
                int br = idx >> 2;
                int bk = (idx & 3) * 4;
                const float4 v = *(const float4*)(Bm + (int64_t)(n0 + br) * ldb + k0 + bk);
                Bs[bk + 0][br] = v.x; Bs[bk + 1][br] = v.y;
                Bs[bk + 2][br] = v.z; Bs[bk + 3][br] = v.w;
            }
        } else {
            #pragma unroll
            for (int i = 0; i < 2; i++) {
                int idx = tid + i * 256;
                int bk = idx >> 5;
                int bn = (idx & 31) * 4;
                const float4 v = *(const float4*)(Bm + (int64_t)(k0 + bk) * ldb + n0 + bn);
                *(float4*)&Bs[bk][bn] = v;
            }
        }
        __syncthreads();

        #pragma unroll
        for (int k = 0; k < BK; k++) {
            float a[8], b[8];
            *(float4*)&a[0] = *(const float4*)&As[k][tm * 8];
            *(float4*)&a[4] = *(const float4*)&As[k][tm * 8 + 4];
            *(float4*)&b[0] = *(const float4*)&Bs[k][tn * 8];
            *(float4*)&b[4] = *(const float4*)&Bs[k][tn * 8 + 4];
            #pragma unroll
            for (int i = 0; i < 8; i++)
                #pragma unroll
                for (int j = 0; j < 8; j++)
                    acc[i][j] += a[i] * b[j];
        }
        __syncthreads();
    }

    float bv[8];
    #pragma unroll
    for (int j = 0; j < 8; j++) {
        int n = n0 + tn * 8 + j;
        float b = 0.0f;
        if (bias1) b += bias1[n];
        if (bias2) b += bias2[n];
        bv[j] = b;
    }
    #pragma unroll
    for (int i = 0; i < 8; i++) {
        int64_t m = m0 + tm * 8 + i;
        float o[8];
        #pragma unroll
        for (int j = 0; j < 8; j++) {
            float v = acc[i][j] + bv[j];
            if (ACT == 1) v = tanhf(v);
            o[j] = v;
        }
        *(float4*)(C + m * ldc + n0 + tn * 8)     = make_float4(o[0], o[1], o[2], o[3]);
        *(float4*)(C + m * ldc + n0 + tn * 8 + 4) = make_float4(o[4], o[5], o[6], o[7]);
    }
}

// ---------------------------------------------------------------------------
// LSTM recurrence (R11: MFMA dot phase).  512 threads = 8 waves, 1 WG/CU.
// A-frags from AGPR/VGPR (reg), LDS, or L2 stream; B = h broadcast; D col0
// lanes write the 16 gate rows of each tile to gsh2.  Ag bias prefetched
// one step ahead into registers, added in the tail.
__global__ __launch_bounds__(512)
__attribute__((amdgpu_waves_per_eu(2, 2)))
void lstm_rec_kernel(
    const float* __restrict__ Ag,
    const uint4* __restrict__ Wpk,
    const float* __restrict__ h0l,
    const float* __restrict__ c0l,
    float* __restrict__ X, int ldx)
{
    const int b    = blockIdx.x;
    const int tid  = threadIdx.x;
    const int w    = tid >> 6;
    const int lane = tid & 63;
    const int s    = w & 1;
    const int r    = w >> 1;
    const int quad = lane >> 4;

    __shared__ __align__(16) uint4  wlds[8 * LFRAG * 64];  // 144 KB
    __shared__ __align__(16) float  gsh2[2 * GATES];       // 8 KB
    __shared__ __align__(16) half_t hsh[HT];               // 512 B

    // --- init: register-resident frags (MFMA A operands -> AGPR-friendly)
    f16x8 wreg[RFRAG];
    #pragma unroll
    for (int i = 0; i < RFRAG; i++)
        wreg[i] = __builtin_bit_cast(f16x8, Wpk[(w * 64 + i) * 64 + lane]);
    // --- LDS-resident frags
    #pragma unroll
    for (int j = 0; j < LFRAG; j++)
        wlds[(w * LFRAG + j) * 64 + lane] = Wpk[(w * 64 + RFRAG + j) * 64 + lane];

    if (tid < HT) hsh[tid] = (half_t)h0l[b * HT + tid];
    float c = (tid < HT) ? c0l[b * HT + tid] : 0.0f;

    const float* AgB = Ag + (int64_t)b * TT * GATES;
    float ac0 = 0.f, ac1 = 0.f, ac2 = 0.f, ac3 = 0.f;
    if (tid < HT) {
        ac0 = AgB[tid];
        ac1 = AgB[HT + tid];
        ac2 = AgB[2 * HT + tid];
        ac3 = AgB[3 * HT + tid];
    }
    __syncthreads();

    const char*  hB    = (const char*)hsh + 256 * s + 16 * quad;
    const uint4* WsB   = Wpk + ((w * 64 + RFRAG + LFRAG) * 64 + lane);
    const uint4* wldsB = &wlds[(w * LFRAG) * 64 + lane];

    #pragma unroll 1
    for (int st = 0; st < TT; st++) {
        // prefetch next step's Ag rows (tail consumes ac* this step)
        float an0 = 0.f, an1 = 0.f, an2 = 0.f, an3 = 0.f;
        {
            int stn = (st + 1 < TT) ? st + 1 : st;
            const float* An = AgB + (int64_t)stn * GATES;
            if (tid < HT) {
                an0 = An[tid];
                an1 = An[HT + tid];
                an2 = An[2 * HT + tid];
                an3 = An[3 * HT + tid];
            }
        }
        // B frags: h chunk, broadcast across cols (quad-dependent only)
        f16x8 bf[4];
        #pragma unroll
        for (int kt = 0; kt < 4; kt++)
            bf[kt] = *(const f16x8*)(hB + kt * 64);

        f16x8 wstr[SFRAG];
        #pragma unroll
        for (int g = 0; g < 4; g++) {
            if (g == 1) {   // stream frags for g=2 (rt 10,11 kt3)
                wstr[0] = __builtin_bit_cast(f16x8, WsB[0 * 64]);
                wstr[1] = __builtin_bit_cast(f16x8, WsB[1 * 64]);
            }
            if (g == 2) {   // stream frags for g=3 (rt 12..15 kt3)
                wstr[2] = __builtin_bit_cast(f16x8, WsB[2 * 64]);
                wstr[3] = __builtin_bit_cast(f16x8, WsB[3 * 64]);
                wstr[4] = __builtin_bit_cast(f16x8, WsB[4 * 64]);
                wstr[5] = __builtin_bit_cast(f16x8, WsB[5 * 64]);
            }
            f32x4 acc[4] = {};
            #pragma unroll
            for (int kt = 0; kt < 4; kt++) {
                #pragma unroll
                for (int i = 0; i < 4; i++) {
                    const int rt = g * 4 + i;
                    f16x8 a;
                    if (kt < 2) {
                        a = wreg[rt * 2 + kt];
                    } else if (kt == 2) {
                        if (rt < 8) a = wreg[32 + rt];
                        else        a = *(const f16x8*)(wldsB + (rt - 8) * 64);
                    } else {
                        if (rt < 10) a = *(const f16x8*)(wldsB + (8 + rt) * 64);
                        else         a = wstr[rt - 10];
                    }
                    acc[i] = __builtin_amdgcn_mfma_f32_16x16x32_f16(
                                 a, bf[kt], acc[i], 0, 0, 0);
                }
            }
            if ((lane & 15) == 0) {
                #pragma unroll
                for (int i = 0; i < 4; i++)
                    *(f32x4*)&gsh2[s * GATES + 256 * r + (g * 4 + i) * 16 + quad * 4]
                        = acc[i];
            }
        }
        WG_BARRIER();

        if (tid < HT) {
            float gi = gsh2[tid]          + gsh2[GATES + tid]          + ac0;
            float gf = gsh2[HT + tid]     + gsh2[GATES + HT + tid]     + ac1;
            float gg = gsh2[2 * HT + tid] + gsh2[GATES + 2 * HT + tid] + ac2;
            float go = gsh2[3 * HT + tid] + gsh2[GATES + 3 * HT + tid] + ac3;
            c = fast_sig(gf) * c + fast_sig(gi) * fast_tanh(gg);
            float h = fast_sig(go) * fast_tanh(c);
            X[((int64_t)b * TT + st) * ldx + tid] = h;
            hsh[tid] = (half_t)h;
        }
        ac0 = an0; ac1 = an1; ac2 = an2; ac3 = an3;
        WG_BARRIER();
    }
}

// ---------------------------------------------------------------------------
__global__ __launch_bounds__(256) void softmax512_kernel(float* __restrict__ S)
{
    int row = blockIdx.x * 4 + (threadIdx.x >> 6);
    int lane = threadIdx.x & 63;
    float* p = S + (int64_t)row * 512 + lane * 8;
    float4 v0 = *(float4*)p;
    float4 v1 = *(float4*)(p + 4);
    float m = fmaxf(fmaxf(fmaxf(v0.x, v0.y), fmaxf(v0.z, v0.w)),
                    fmaxf(fmaxf(v1.x, v1.y), fmaxf(v1.z, v1.w)));
    #pragma unroll
    for (int off = 32; off; off >>= 1) m = fmaxf(m, __shfl_xor(m, off));
    v0.x = __expf(v0.x - m); v0.y = __expf(v0.y - m);
    v0.z = __expf(v0.z - m); v0.w = __expf(v0.w - m);
    v1.x = __expf(v1.x - m); v1.y = __expf(v1.y - m);
    v1.z = __expf(v1.z - m); v1.w = __expf(v1.w - m);
    float s = v0.x + v0.y + v0.z + v0.w + v1.x + v1.y + v1.z + v1.w;
    #pragma unroll
    for (int off = 32; off; off >>= 1) s += __shfl_xor(s, off);
    float inv = 1.0f / s;
    v0.x *= inv; v0.y *= inv; v0.z *= inv; v0.w *= inv;
    v1.x *= inv; v1.y *= inv; v1.z *= inv; v1.w *= inv;
    *(float4*)p = v0;
    *(float4*)(p + 4) = v1;
}

__global__ __launch_bounds__(256) void values_kernel(
    const float* __restrict__ Q, const float* __restrict__ L, float* __restrict__ V)
{
    int row = blockIdx.x * 4 + (threadIdx.x >> 6);
    int lane = threadIdx.x & 63;
    float2 q = *(const float2*)(Q + (int64_t)row * OO + lane * 2);
    float2 l = *(const float2*)(L + (int64_t)row * OO + lane * 2);
    float s = q.x * l.x + q.y * l.y;
    #pragma unroll
    for (int off = 32; off; off >>= 1) s += __shfl_xor(s, off);
    if (lane == 0) V[row] = s;
}

// ---------------------------------------------------------------------------
extern "C" void kernel_launch(void* const* d_in, const int* in_sizes, int n_in,
                              void* d_out, int out_size, void* d_ws, size_t ws_size,
                              hipStream_t stream)
{
    const float* enc      = (const float*)d_in[0];
    const float* h0       = (const float*)d_in[1];
    const float* c0       = (const float*)d_in[2];
    const int*   actions  = (const int*)  d_in[3];
    const float* emb_t    = (const float*)d_in[4];
    const float* Wih      = (const float*)d_in[5];
    const float* Whh      = (const float*)d_in[6];
    const float* bih      = (const float*)d_in[7];
    const float* bhh      = (const float*)d_in[8];
    const float* W_attn   = (const float*)d_in[9];
    const float* b_attn   = (const float*)d_in[10];
    const float* W_concat = (const float*)d_in[11];
    const float* b_concat = (const float*)d_in[12];
    const float* W_out    = (const float*)d_in[13];
    const float* W_critic = (const float*)d_in[14];
    const float* b_critic = (const float*)d_in[15];
    (void)in_sizes; (void)n_in; (void)out_size; (void)ws_size;

    const int M = BB * TT;                 // 32768

    float* out    = (float*)d_out;
    float* dact   = out;
    float* logits = out + M;
    float* values = out + M + (int64_t)M * OO;

    float* ws    = (float*)d_ws;
    float* gates = ws;
    float* xbuf  = ws + 33554432;
    float* cat   = ws + 41943040;
    float* keysR = ws + 58720256;
    float* keys  = keysR;
    uint4* Wpkh  = (uint4*)keysR;          // 1 MB; dead before keys
    float* scores = gates;
    float* qv     = gates;
    float* dec    = xbuf;

    const int64_t LWP = 32768;             // uint4s per layer in Wpkh
    const int64_t LW  = (int64_t)GATES * HT;

    // 1) embedding + decoder_action
    hipLaunchKernelGGL(embed_kernel, dim3(M), dim3(256), 0, stream,
                       actions, emb_t, xbuf, dact);
    // 2) repack Whh to fp16 MFMA fragment layout
    hipLaunchKernelGGL(repack_whh_mfma_kernel, dim3(256), dim3(256), 0, stream,
                       Whh, Wpkh);
    // 3) layer-0 input GEMM (MFMA fp16): gates = emb @ Wih0^T + bih0 + bhh0
    hipLaunchKernelGGL((mfma_gemm_kernel<true, 0>), dim3(8, 256, 1), dim3(256), 0, stream,
                       xbuf, Wih, gates, HT, HT, HT, GATES,
                       (int64_t)0, (int64_t)0, (int64_t)0, bih, bhh);
    // 4) layer-0 recurrence -> X1 (xbuf, ldx=256)
    hipLaunchKernelGGL(lstm_rec_kernel, dim3(BB), dim3(512), 0, stream,
                       gates, Wpkh, h0, c0, xbuf, HT);
    // 5) layer-1 input GEMM (MFMA fp16)
    hipLaunchKernelGGL((mfma_gemm_kernel<true, 0>), dim3(8, 256, 1), dim3(256), 0, stream,
                       xbuf, Wih + LW, gates, HT, HT, HT, GATES,
                       (int64_t)0, (int64_t)0, (int64_t)0, bih + GATES, bhh + GATES);
    // 6) layer-1 recurrence -> cat[:, 0:256] (ldx=512)
    hipLaunchKernelGGL(lstm_rec_kernel, dim3(BB), dim3(512), 0, stream,
                       gates, Wpkh + LWP, h0 + BB * HT, c0 + BB * HT, cat, 2 * HT);
    // 7) keys = enc @ W_attn^T + b_attn (MFMA fp16; overwrites Wpkh region)
    hipLaunchKernelGGL((mfma_gemm_kernel<true, 0>), dim3(2, 256, 1), dim3(256), 0, stream,
                       enc, W_attn, keys, HT, HT, HT, HT,
                       (int64_t)0, (int64_t)0, (int64_t)0, b_attn, (const float*)nullptr);
    // 8) scores[b] = out[b] @ keys[b]^T  (fp32, precision-sensitive softmax input)
    hipLaunchKernelGGL((gemm128_kernel<true, 0>), dim3(4, 4, BB), dim3(256), 0, stream,
                       cat, keys, scores, HT, 2 * HT, HT, TT,
                       (int64_t)TT * 2 * HT, (int64_t)TT * HT, (int64_t)TT * TT,
                       (const float*)nullptr, (const float*)nullptr);
    // 9) softmax
    hipLaunchKernelGGL(softmax512_kernel, dim3(M / 4), dim3(256), 0, stream, scores);
    // 10) ctx[b] = P[b] @ enc[b] -> cat[:,256:]  (fp32)
    hipLaunchKernelGGL((gemm128_kernel<false, 0>), dim3(2, 4, BB), dim3(256), 0, stream,
                       scores, enc, cat + HT, TT, TT, HT, 2 * HT,
                       (int64_t)TT * TT, (int64_t)TT * HT, (int64_t)TT * 2 * HT,
                       (const float*)nullptr, (const float*)nullptr);
    // 11) dec = tanh(cat @ W_concat^T + b_concat) (MFMA fp16)
    hipLaunchKernelGGL((mfma_gemm_kernel<true, 1>), dim3(2, 256, 1), dim3(256), 0, stream,
                       cat, W_concat, dec, 2 * HT, 2 * HT, 2 * HT, HT,
                       (int64_t)0, (int64_t)0, (int64_t)0, b_concat, (const float*)nullptr);
    // 12) logits = dec @ W_out^T  (fp32 — output path)
    hipLaunchKernelGGL((gemm128_kernel<true, 0>), dim3(1, 256, 1), dim3(256), 0, stream,
                       dec, W_out, logits, HT, HT, HT, OO,
                       (int64_t)0, (int64_t)0, (int64_t)0,
                       (const float*)nullptr, (const float*)nullptr);
    // 13) qv = logits @ W_critic^T + b_critic  (fp32 — output path)
    hipLaunchKernelGGL((gemm128_kernel<true, 0>), dim3(1, 256, 1), dim3(256), 0, stream,
                       logits, W_critic, qv, OO, OO, OO, OO,
                       (int64_t)0, (int64_t)0, (int64_t)0, b_critic, (const float*)nullptr);
    // 14) values
    hipLaunchKernelGGL(values_kernel, dim3(M / 4), dim3(256), 0, stream,
                       qv, logits, values);
}

// Round 3
// 2447.140 us; speedup vs baseline: 1.0058x; 1.0058x over previous
//
#include <hip/hip_runtime.h>
#include <stdint.h>

// Problem constants
#define BB   64
#define TT   512
#define HT   256
#define OO   128
#define GATES 1024   // 4*H

// ---------------------------------------------------------------------------
// R12 recurrence: MFMA-based (R11 structure), delivery-schedule fixed.
// gates[1024] = Whh[1024x256] @ h[256] per block (one batch element).
// 8 waves: s=w&1 owns k-half, r=w>>1 owns row quarter. Per wave 16 row-tiles
// (rt) x 4 k-tiles (kt) of mfma_f32_16x16x32_f16; B = h chunk broadcast into
// all 16 cols; col-0 lanes store D.
// R11 lesson: 40/18/6 reg/LDS/stream with mid-loop stream loads stalled the
// g-loop on vmcnt (960us, step 4500cy vs ~1400cy LDS floor). R12: 44/18/2 —
// stream cut to 16KB/step, prefetched at step START and consumed in the LAST
// chain group; reg frags feed chain heads, LDS frags chain tails.
// Frag membership (rt,kt): kt<2 -> REG rt*2+kt (0..31); kt==2 -> rt<12 REG
// 32+rt (32..43), rt>=12 LDS rt-12 (0..3); kt==3 -> rt<14 LDS 4+rt (4..17),
// rt>=14 STREAM rt-14 (0..1).
#define RFRAG 44
#define LFRAG 18
#define SFRAG 2

typedef _Float16 half_t;
typedef _Float16 half2_t __attribute__((ext_vector_type(2)));
typedef _Float16 f16x8  __attribute__((ext_vector_type(8)));
typedef float    f32x4  __attribute__((ext_vector_type(4)));

// lgkm-only workgroup barrier (R9 win): no vmcnt drain per step.
#define WG_BARRIER() do { __builtin_amdgcn_s_waitcnt(0xC07F); \
                          __builtin_amdgcn_s_barrier(); } while (0)

__device__ __forceinline__ float fast_sig(float x) {
    return __builtin_amdgcn_rcpf(1.0f + __expf(-x));
}
__device__ __forceinline__ float fast_tanh(float x) {
    float t = __expf(2.0f * x);
    return 1.0f - 2.0f * __builtin_amdgcn_rcpf(t + 1.0f);
}

// ---------------------------------------------------------------------------
// Embedding gather + decoder_action output
__global__ __launch_bounds__(256) void embed_kernel(
    const int* __restrict__ actions, const float* __restrict__ emb_table,
    float* __restrict__ X, float* __restrict__ dact)
{
    int row = blockIdx.x;
    int t = row & (TT - 1);
    int id = (t == 0) ? 0 : actions[row - 1];
    X[(int64_t)row * HT + threadIdx.x] = emb_table[(int64_t)id * HT + threadIdx.x];
    if (threadIdx.x == 0) dact[row] = (float)actions[row];
}

// ---------------------------------------------------------------------------
// Repack Whh to fp16 MFMA A-fragment layout (R12 frag membership).
// Output index (per layer, 32768 uint4): (w*64 + pos)*64 + lane.
// pos: REG idx (0..43), 44+LDS idx (44..61), 62+STREAM idx (62,63).
// Lane holds A[row= 256r+16rt+(lane&15)][k= 128s+32kt+(lane>>4)*8 .. +7].
__global__ __launch_bounds__(256) void repack_whh_mfma_kernel(
    const float* __restrict__ Whh, uint4* __restrict__ Wpkh)
{
    int idx  = blockIdx.x * 256 + threadIdx.x;  // 0..65535
    int lane = idx & 63;
    int f    = (idx >> 6) & 63;
    int w    = (idx >> 12) & 7;
    int l    = idx >> 15;
    int s = w & 1, r = w >> 1;
    int rt = f >> 2, kt = f & 3;

    int pos;
    if (kt < 2)       pos = rt * 2 + kt;                         // REG 0..31
    else if (kt == 2) pos = (rt < 12) ? (32 + rt)                // REG 32..43
                                      : (44 + (rt - 12));        // LDS 0..3
    else              pos = (rt < 14) ? (44 + 4 + rt)            // LDS 4..17
                                      : (62 + (rt - 14));        // STREAM 0..1

    int row  = 256 * r + 16 * rt + (lane & 15);
    int kcol = 128 * s + 32 * kt + (lane >> 4) * 8;
    const float* src = Whh + (int64_t)l * (GATES * HT) + (int64_t)row * HT + kcol;
    const float4 a = *(const float4*)(src);
    const float4 b = *(const float4*)(src + 4);
    half2_t p0 = {(half_t)a.x, (half_t)a.y};
    half2_t p1 = {(half_t)a.z, (half_t)a.w};
    half2_t p2 = {(half_t)b.x, (half_t)b.y};
    half2_t p3 = {(half_t)b.z, (half_t)b.w};
    uint4 o;
    o.x = __builtin_bit_cast(unsigned int, p0);
    o.y = __builtin_bit_cast(unsigned int, p1);
    o.z = __builtin_bit_cast(unsigned int, p2);
    o.w = __builtin_bit_cast(unsigned int, p3);
    Wpkh[(int64_t)l * 32768 + ((w * 64 + pos) * 64 + lane)] = o;
}

// ---------------------------------------------------------------------------
// MFMA fp16 GEMM: C = act( A @ op(B) + bias1 + bias2 ), fp32 in/out.
template<bool TRANS_B, int ACT>
__global__ __launch_bounds__(256) void mfma_gemm_kernel(
    const float* __restrict__ A, const float* __restrict__ Bm,
    float* __restrict__ C,
    int K, int lda, int ldb, int ldc,
    int64_t sA, int64_t sB, int64_t sC,
    const float* __restrict__ bias1, const float* __restrict__ bias2)
{
    constexpr int BM = 128, BN = 128, BK = 32;
    constexpr int LDT = BK + 8;                  // 40 halfs = 80 B row stride
    __shared__ __align__(16) half_t Asl[BM * LDT];   // 10 KB
    __shared__ __align__(16) half_t Bsl[BN * LDT];   // 10 KB

    const int tid  = threadIdx.x;
    const int wave = tid >> 6;
    const int lane = tid & 63;
    const int wm = (wave & 1) * 64;
    const int wn = (wave >> 1) * 64;
    const int m0 = blockIdx.y * BM;
    const int n0 = blockIdx.x * BN;
    A  += (int64_t)blockIdx.z * sA;
    Bm += (int64_t)blockIdx.z * sB;
    C  += (int64_t)blockIdx.z * sC;

    const int fm = lane & 15;
    const int qd = lane >> 4;

    f32x4 acc[4][4] = {};

    for (int k0 = 0; k0 < K; k0 += BK) {
        #pragma unroll
        for (int i = 0; i < 4; i++) {
            int idx = tid + i * 256;             // 0..1023
            int r  = idx >> 3;                   // 0..127
            int kq = idx & 7;                    // 0..7
            float4 v = *(const float4*)(A + (int64_t)(m0 + r) * lda + k0 + kq * 4);
            half_t* d = &Asl[r * LDT + kq * 4];
            d[0] = (half_t)v.x; d[1] = (half_t)v.y;
            d[2] = (half_t)v.z; d[3] = (half_t)v.w;
        }
        if (TRANS_B) {
            #pragma unroll
            for (int i = 0; i < 4; i++) {
                int idx = tid + i * 256;
                int r  = idx >> 3;
                int kq = idx & 7;
                float4 v = *(const float4*)(Bm + (int64_t)(n0 + r) * ldb + k0 + kq * 4);
                half_t* d = &Bsl[r * LDT + kq * 4];
                d[0] = (half_t)v.x; d[1] = (half_t)v.y;
                d[2] = (half_t)v.z; d[3] = (half_t)v.w;
            }
        } else {
            #pragma unroll
            for (int i = 0; i < 4; i++) {
                int idx = tid + i * 256;
                int kk = idx >> 5;               // 0..31
                int nq = idx & 31;               // 0..31 (x4 n)
                float4 v = *(const float4*)(Bm + (int64_t)(k0 + kk) * ldb + n0 + nq * 4);
                Bsl[(nq * 4 + 0) * LDT + kk] = (half_t)v.x;
                Bsl[(nq * 4 + 1) * LDT + kk] = (half_t)v.y;
                Bsl[(nq * 4 + 2) * LDT + kk] = (half_t)v.z;
                Bsl[(nq * 4 + 3) * LDT + kk] = (half_t)v.w;
            }
        }
        __syncthreads();

        f16x8 af[4], bf[4];
        #pragma unroll
        for (int t = 0; t < 4; t++)
            af[t] = *(const f16x8*)&Asl[(wm + t * 16 + fm) * LDT + qd * 8];
        #pragma unroll
        for (int t = 0; t < 4; t++)
            bf[t] = *(const f16x8*)&Bsl[(wn + t * 16 + fm) * LDT + qd * 8];
        #pragma unroll
        for (int mt = 0; mt < 4; mt++)
            #pragma unroll
            for (int nt = 0; nt < 4; nt++)
                acc[mt][nt] = __builtin_amdgcn_mfma_f32_16x16x32_f16(
                                  af[mt], bf[nt], acc[mt][nt], 0, 0, 0);
        __syncthreads();
    }

    #pragma unroll
    for (int nt = 0; nt < 4; nt++) {
        int n = n0 + wn + nt * 16 + fm;
        float bv = 0.0f;
        if (bias1) bv += bias1[n];
        if (bias2) bv += bias2[n];
        #pragma unroll
        for (int mt = 0; mt < 4; mt++) {
            #pragma unroll
            for (int r = 0; r < 4; r++) {
                int m = m0 + wm + mt * 16 + qd * 4 + r;
                float v = acc[mt][nt][r] + bv;
                if (ACT == 1) v = tanhf(v);
                C[(int64_t)m * ldc + n] = v;
            }
        }
    }
}

// ---------------------------------------------------------------------------
// Generic fp32 tiled GEMM (kept for attention + output chain precision).
template<bool TRANS_B, int ACT>
__global__ __launch_bounds__(256) void gemm128_kernel(
    const float* __restrict__ A, const float* __restrict__ Bm,
    float* __restrict__ C,
    int K, int lda, int ldb, int ldc,
    int64_t sA, int64_t sB, int64_t sC,
    const float* __restrict__ bias1, const float* __restrict__ bias2)
{
    constexpr int BM = 128, BN = 128, BK = 16;
    __shared__ __align__(16) float As[BK][BM + 4];
    __shared__ __align__(16) float Bs[BK][BN + 4];

    const int tid = threadIdx.x;
    const int m0 = blockIdx.y * BM;
    const int n0 = blockIdx.x * BN;
    A  += (int64_t)blockIdx.z * sA;
    Bm += (int64_t)blockIdx.z * sB;
    C  += (int64_t)blockIdx.z * sC;

    const int tm = tid & 15;
    const int tn = tid >> 4;

    float acc[8][8] = {};

    for (int k0 = 0; k0 < K; k0 += BK) {
        #pragma unroll
        for (int i = 0; i < 2; i++) {
            int idx = tid + i * 256;
            int ar = idx >> 2;
            int ak = (idx & 3) * 4;
            const float4 v = *(const float4*)(A + (int64_t)(m0 + ar) * lda + k0 + ak);
            As[ak + 0][ar] = v.x; As[ak + 1][ar] = v.y;
            As[ak + 2][ar] = v.z; As[ak + 3][ar] = v.w;
        }
        if (TRANS_B) {
            #pragma unroll
            for (int i = 0; i < 2; i++) {
                int idx = tid + i * 256;
                int br = idx >> 2;
                int bk = (idx & 3) * 4;
                const float4 v = *(const float4*)(Bm + (int64_t)(n0 + br) * ldb + k0 + bk);
                Bs[bk + 0][br] = v.x; Bs[bk + 1][br] = v.y;
                Bs[bk + 2][br] = v.z; Bs[bk + 3][br] = v.w;
            }
        } else {
            #pragma unroll
            for (int i = 0; i < 2; i++) {
                int idx = tid + i * 256;
                int bk = idx >> 5;
                int bn = (idx & 31) * 4;
                const float4 v = *(const float4*)(Bm + (int64_t)(k0 + bk) * ldb + n0 + bn);
                *(float4*)&Bs[bk][bn] = v;
            }
        }
        __syncthreads();

        #pragma unroll
        for (int k = 0; k < BK; k++) {
            float a[8], b[8];
            *(float4*)&a[0] = *(const float4*)&As[k][tm * 8];
            *(float4*)&a[4] = *(const float4*)&As[k][tm * 8 + 4];
            *(float4*)&b[0] = *(const float4*)&Bs[k][tn * 8];
            *(float4*)&b[4] = *(const float4*)&Bs[k][tn * 8 + 4];
            #pragma unroll
            for (int i = 0; i < 8; i++)
                #pragma unroll
                for (int j = 0; j < 8; j++)
                    acc[i][j] += a[i] * b[j];
        }
        __syncthreads();
    }

    float bv[8];
    #pragma unroll
    for (int j = 0; j < 8; j++) {
        int n = n0 + tn * 8 + j;
        float b = 0.0f;
        if (bias1) b += bias1[n];
        if (bias2) b += bias2[n];
        bv[j] = b;
    }
    #pragma unroll
    for (int i = 0; i < 8; i++) {
        int64_t m = m0 + tm * 8 + i;
        float o[8];
        #pragma unroll
        for (int j = 0; j < 8; j++) {
            float v = acc[i][j] + bv[j];
            if (ACT == 1) v = tanhf(v);
            o[j] = v;
        }
        *(float4*)(C + m * ldc + n0 + tn * 8)     = make_float4(o[0], o[1], o[2], o[3]);
        *(float4*)(C + m * ldc + n0 + tn * 8 + 4) = make_float4(o[4], o[5], o[6], o[7]);
    }
}

// ---------------------------------------------------------------------------
// LSTM recurrence (R12).  512 threads = 8 waves, 1 WG/CU, 2 waves/EU.
__global__ __launch_bounds__(512)
__attribute__((amdgpu_waves_per_eu(2, 2)))
void lstm_rec_kernel(
    const float* __restrict__ Ag,
    const uint4* __restrict__ Wpk,
    const float* __restrict__ h0l,
    const float* __restrict__ c0l,
    float* __restrict__ X, int ldx)
{
    const int b    = blockIdx.x;
    const int tid  = threadIdx.x;
    const int w    = tid >> 6;
    const int lane = tid & 63;
    const int s    = w & 1;
    const int r    = w >> 1;
    const int quad = lane >> 4;

    __shared__ __align__(16) uint4  wlds[8 * LFRAG * 64];  // 144 KB
    __shared__ __align__(16) float  gsh2[2 * GATES];       // 8 KB
    __shared__ __align__(16) half_t hsh[HT];               // 512 B

    // --- init: register-resident frags (MFMA A operands -> AGPR)
    f16x8 wreg[RFRAG];
    #pragma unroll
    for (int i = 0; i < RFRAG; i++)
        wreg[i] = __builtin_bit_cast(f16x8, Wpk[(w * 64 + i) * 64 + lane]);
    // --- LDS-resident frags
    #pragma unroll
    for (int j = 0; j < LFRAG; j++)
        wlds[(w * LFRAG + j) * 64 + lane] = Wpk[(w * 64 + RFRAG + j) * 64 + lane];

    if (tid < HT) hsh[tid] = (half_t)h0l[b * HT + tid];
    float c = (tid < HT) ? c0l[b * HT + tid] : 0.0f;

    const float* AgB = Ag + (int64_t)b * TT * GATES;
    float ac0 = 0.f, ac1 = 0.f, ac2 = 0.f, ac3 = 0.f;
    if (tid < HT) {
        ac0 = AgB[tid];
        ac1 = AgB[HT + tid];
        ac2 = AgB[2 * HT + tid];
        ac3 = AgB[3 * HT + tid];
    }
    __syncthreads();

    const char*  hB    = (const char*)hsh + 256 * s + 16 * quad;
    const uint4* WsB   = Wpk + ((w * 64 + RFRAG + LFRAG) * 64 + lane);
    const uint4* wldsB = &wlds[(w * LFRAG) * 64 + lane];

    #pragma unroll 1
    for (int st = 0; st < TT; st++) {
        // stream frags for the LAST chain group (kt3 of rt 14,15): issued
        // here, consumed ~3 chain-groups later -> L2 latency fully hidden,
        // no vmcnt waits mid-loop.
        f16x8 wstr0 = __builtin_bit_cast(f16x8, WsB[0 * 64]);
        f16x8 wstr1 = __builtin_bit_cast(f16x8, WsB[1 * 64]);

        // prefetch next step's Ag rows (tail consumes ac* this step)
        float an0 = 0.f, an1 = 0.f, an2 = 0.f, an3 = 0.f;
        {
            int stn = (st + 1 < TT) ? st + 1 : st;
            const float* An = AgB + (int64_t)stn * GATES;
            if (tid < HT) {
                an0 = An[tid];
                an1 = An[HT + tid];
                an2 = An[2 * HT + tid];
                an3 = An[3 * HT + tid];
            }
        }
        // B frags: h chunk, broadcast across cols (quad-dependent only)
        f16x8 bf[4];
        #pragma unroll
        for (int kt = 0; kt < 4; kt++)
            bf[kt] = *(const f16x8*)(hB + kt * 64);

        #pragma unroll
        for (int g = 0; g < 4; g++) {
            f32x4 acc[4] = {};
            #pragma unroll
            for (int kt = 0; kt < 4; kt++) {
                #pragma unroll
                for (int i = 0; i < 4; i++) {
                    const int rt = g * 4 + i;
                    f16x8 a;
                    if (kt < 2) {
                        a = wreg[rt * 2 + kt];
                    } else if (kt == 2) {
                        if (rt < 12) a = wreg[32 + rt];
                        else         a = *(const f16x8*)(wldsB + (rt - 12) * 64);
                    } else {
                        if (rt < 14)      a = *(const f16x8*)(wldsB + (4 + rt) * 64);
                        else if (rt == 14) a = wstr0;
                        else               a = wstr1;
                    }
                    acc[i] = __builtin_amdgcn_mfma_f32_16x16x32_f16(
                                 a, bf[kt], acc[i], 0, 0, 0);
                }
            }
            if ((lane & 15) == 0) {
                #pragma unroll
                for (int i = 0; i < 4; i++)
                    *(f32x4*)&gsh2[s * GATES + 256 * r + (g * 4 + i) * 16 + quad * 4]
                        = acc[i];
            }
        }
        WG_BARRIER();

        if (tid < HT) {
            float gi = gsh2[tid]          + gsh2[GATES + tid]          + ac0;
            float gf = gsh2[HT + tid]     + gsh2[GATES + HT + tid]     + ac1;
            float gg = gsh2[2 * HT + tid] + gsh2[GATES + 2 * HT + tid] + ac2;
            float go = gsh2[3 * HT + tid] + gsh2[GATES + 3 * HT + tid] + ac3;
            c = fast_sig(gf) * c + fast_sig(gi) * fast_tanh(gg);
            float h = fast_sig(go) * fast_tanh(c);
            X[((int64_t)b * TT + st) * ldx + tid] = h;
            hsh[tid] = (half_t)h;
        }
        ac0 = an0; ac1 = an1; ac2 = an2; ac3 = an3;
        WG_BARRIER();
    }
}

// ---------------------------------------------------------------------------
__global__ __launch_bounds__(256) void softmax512_kernel(float* __restrict__ S)
{
    int row = blockIdx.x * 4 + (threadIdx.x >> 6);
    int lane = threadIdx.x & 63;
    float* p = S + (int64_t)row * 512 + lane * 8;
    float4 v0 = *(float4*)p;
    float4 v1 = *(float4*)(p + 4);
    float m = fmaxf(fmaxf(fmaxf(v0.x, v0.y), fmaxf(v0.z, v0.w)),
                    fmaxf(fmaxf(v1.x, v1.y), fmaxf(v1.z, v1.w)));
    #pragma unroll
    for (int off = 32; off; off >>= 1) m = fmaxf(m, __shfl_xor(m, off));
    v0.x = __expf(v0.x - m); v0.y = __expf(v0.y - m);
    v0.z = __expf(v0.z - m); v0.w = __expf(v0.w - m);
    v1.x = __expf(v1.x - m); v1.y = __expf(v1.y - m);
    v1.z = __expf(v1.z - m); v1.w = __expf(v1.w - m);
    float s = v0.x + v0.y + v0.z + v0.w + v1.x + v1.y + v1.z + v1.w;
    #pragma unroll
    for (int off = 32; off; off >>= 1) s += __shfl_xor(s, off);
    float inv = 1.0f / s;
    v0.x *= inv; v0.y *= inv; v0.z *= inv; v0.w *= inv;
    v1.x *= inv; v1.y *= inv; v1.z *= inv; v1.w *= inv;
    *(float4*)p = v0;
    *(float4*)(p + 4) = v1;
}

__global__ __launch_bounds__(256) void values_kernel(
    const float* __restrict__ Q, const float* __restrict__ L, float* __restrict__ V)
{
    int row = blockIdx.x * 4 + (threadIdx.x >> 6);
    int lane = threadIdx.x & 63;
    float2 q = *(const float2*)(Q + (int64_t)row * OO + lane * 2);
    float2 l = *(const float2*)(L + (int64_t)row * OO + lane * 2);
    float s = q.x * l.x + q.y * l.y;
    #pragma unroll
    for (int off = 32; off; off >>= 1) s += __shfl_xor(s, off);
    if (lane == 0) V[row] = s;
}

// ---------------------------------------------------------------------------
extern "C" void kernel_launch(void* const* d_in, const int* in_sizes, int n_in,
                              void* d_out, int out_size, void* d_ws, size_t ws_size,
                              hipStream_t stream)
{
    const float* enc      = (const float*)d_in[0];
    const float* h0       = (const float*)d_in[1];
    const float* c0       = (const float*)d_in[2];
    const int*   actions  = (const int*)  d_in[3];
    const float* emb_t    = (const float*)d_in[4];
    const float* Wih      = (const float*)d_in[5];
    const float* Whh      = (const float*)d_in[6];
    const float* bih      = (const float*)d_in[7];
    const float* bhh      = (const float*)d_in[8];
    const float* W_attn   = (const float*)d_in[9];
    const float* b_attn   = (const float*)d_in[10];
    const float* W_concat = (const float*)d_in[11];
    const float* b_concat = (const float*)d_in[12];
    const float* W_out    = (const float*)d_in[13];
    const float* W_critic = (const float*)d_in[14];
    const float* b_critic = (const float*)d_in[15];
    (void)in_sizes; (void)n_in; (void)out_size; (void)ws_size;

    const int M = BB * TT;                 // 32768

    float* out    = (float*)d_out;
    float* dact   = out;
    float* logits = out + M;
    float* values = out + M + (int64_t)M * OO;

    float* ws    = (float*)d_ws;
    float* gates = ws;
    float* xbuf  = ws + 33554432;
    float* cat   = ws + 41943040;
    float* keysR = ws + 58720256;
    float* keys  = keysR;
    uint4* Wpkh  = (uint4*)keysR;          // 1 MB; dead before keys
    float* scores = gates;
    float* qv     = gates;
    float* dec    = xbuf;

    const int64_t LWP = 32768;             // uint4s per layer in Wpkh
    const int64_t LW  = (int64_t)GATES * HT;

    // 1) embedding + decoder_action
    hipLaunchKernelGGL(embed_kernel, dim3(M), dim3(256), 0, stream,
                       actions, emb_t, xbuf, dact);
    // 2) repack Whh to fp16 MFMA fragment layout
    hipLaunchKernelGGL(repack_whh_mfma_kernel, dim3(256), dim3(256), 0, stream,
                       Whh, Wpkh);
    // 3) layer-0 input GEMM (MFMA fp16): gates = emb @ Wih0^T + bih0 + bhh0
    hipLaunchKernelGGL((mfma_gemm_kernel<true, 0>), dim3(8, 256, 1), dim3(256), 0, stream,
                       xbuf, Wih, gates, HT, HT, HT, GATES,
                       (int64_t)0, (int64_t)0, (int64_t)0, bih, bhh);
    // 4) layer-0 recurrence -> X1 (xbuf, ldx=256)
    hipLaunchKernelGGL(lstm_rec_kernel, dim3(BB), dim3(512), 0, stream,
                       gates, Wpkh, h0, c0, xbuf, HT);
    // 5) layer-1 input GEMM (MFMA fp16)
    hipLaunchKernelGGL((mfma_gemm_kernel<true, 0>), dim3(8, 256, 1), dim3(256), 0, stream,
                       xbuf, Wih + LW, gates, HT, HT, HT, GATES,
                       (int64_t)0, (int64_t)0, (int64_t)0, bih + GATES, bhh + GATES);
    // 6) layer-1 recurrence -> cat[:, 0:256] (ldx=512)
    hipLaunchKernelGGL(lstm_rec_kernel, dim3(BB), dim3(512), 0, stream,
                       gates, Wpkh + LWP, h0 + BB * HT, c0 + BB * HT, cat, 2 * HT);
    // 7) keys = enc @ W_attn^T + b_attn (MFMA fp16; overwrites Wpkh region)
    hipLaunchKernelGGL((mfma_gemm_kernel<true, 0>), dim3(2, 256, 1), dim3(256), 0, stream,
                       enc, W_attn, keys, HT, HT, HT, HT,
                       (int64_t)0, (int64_t)0, (int64_t)0, b_attn, (const float*)nullptr);
    // 8) scores[b] = out[b] @ keys[b]^T  (fp32, precision-sensitive softmax input)
    hipLaunchKernelGGL((gemm128_kernel<true, 0>), dim3(4, 4, BB), dim3(256), 0, stream,
                       cat, keys, scores, HT, 2 * HT, HT, TT,
                       (int64_t)TT * 2 * HT, (int64_t)TT * HT, (int64_t)TT * TT,
                       (const float*)nullptr, (const float*)nullptr);
    // 9) softmax
    hipLaunchKernelGGL(softmax512_kernel, dim3(M / 4), dim3(256), 0, stream, scores);
    // 10) ctx[b] = P[b] @ enc[b] -> cat[:,256:]  (fp32)
    hipLaunchKernelGGL((gemm128_kernel<false, 0>), dim3(2, 4, BB), dim3(256), 0, stream,
                       scores, enc, cat + HT, TT, TT, HT, 2 * HT,
                       (int64_t)TT * TT, (int64_t)TT * HT, (int64_t)TT * 2 * HT,
                       (const float*)nullptr, (const float*)nullptr);
    // 11) dec = tanh(cat @ W_concat^T + b_concat) (MFMA fp16)
    hipLaunchKernelGGL((mfma_gemm_kernel<true, 1>), dim3(2, 256, 1), dim3(256), 0, stream,
                       cat, W_concat, dec, 2 * HT, 2 * HT, 2 * HT, HT,
                       (int64_t)0, (int64_t)0, (int64_t)0, b_concat, (const float*)nullptr);
    // 12) logits = dec @ W_out^T  (fp32 — output path)
    hipLaunchKernelGGL((gemm128_kernel<true, 0>), dim3(1, 256, 1), dim3(256), 0, stream,
                       dec, W_out, logits, HT, HT, HT, OO,
                       (int64_t)0, (int64_t)0, (int64_t)0,
                       (const float*)nullptr, (const float*)nullptr);
    // 13) qv = logits @ W_critic^T + b_critic  (fp32 — output path)
    hipLaunchKernelGGL((gemm128_kernel<true, 0>), dim3(1, 256, 1), dim3(256), 0, stream,
                       logits, W_critic, qv, OO, OO, OO, OO,
                       (int64_t)0, (int64_t)0, (int64_t)0, b_critic, (const float*)nullptr);
    // 14) values
    hipLaunchKernelGGL(values_kernel, dim3(M / 4), dim3(256), 0, stream,
                       qv, logits, values);
}